// Round 10
// baseline (282.180 us; speedup 1.0000x reference)
//
#include <hip/hip_runtime.h>
#include <hip/hip_fp16.h>

#define DIMC 768
#define NH 4
#define HD 192
#define SEQ 2048
#define NBATCH 8
#define SCALE_F 0.07216878364870323f  /* 192^-0.5 */
#define LOG2E   1.4426950408889634f
#define DEFER_THR 8.0f                /* log2-domain defer-max threshold */

typedef _Float16 f16x8 __attribute__((ext_vector_type(8)));
typedef _Float16 f16x4 __attribute__((ext_vector_type(4)));
typedef float    f32x4 __attribute__((ext_vector_type(4)));

__device__ __forceinline__ f32x4 mfma16(f16x8 a, f16x8 b, f32x4 c) {
    return __builtin_amdgcn_mfma_f32_16x16x32_f16(a, b, c, 0, 0, 0);
}
__device__ __forceinline__ void gl16(const void* g, void* l) {
    __builtin_amdgcn_global_load_lds(
        (const __attribute__((address_space(1))) unsigned int*)g,
        (__attribute__((address_space(3))) unsigned int*)l, 16, 0, 0);
}
__device__ __forceinline__ float exp2_hw(float x) {
    return __builtin_amdgcn_exp2f(x);
}

// ---------------------------------------------------------------------------
// cvt_w: fp32 W[768][768] -> fp16 pre-swizzled 256-row tile images.
// offset = ((nt*12 + t)*256 + rr)*64 + (cc ^ ((rr&7)<<3)).
// ---------------------------------------------------------------------------
__global__ __launch_bounds__(256)
void cvt_w(const float* __restrict__ w0, const float* __restrict__ w1,
           const float* __restrict__ w2, const float* __restrict__ w3,
           _Float16* __restrict__ o0, _Float16* __restrict__ o1,
           _Float16* __restrict__ o2, _Float16* __restrict__ o3)
{
    const float* src = (blockIdx.y == 0) ? w0 : (blockIdx.y == 1) ? w1
                     : (blockIdx.y == 2) ? w2 : w3;
    _Float16* dst = (blockIdx.y == 0) ? o0 : (blockIdx.y == 1) ? o1
                  : (blockIdx.y == 2) ? o2 : o3;
    const int e   = blockIdx.x * 256 + threadIdx.x;
    const int row = e / 192;
    const int col = (e - row * 192) * 4;
    const float4 v = *(const float4*)(src + (size_t)row * DIMC + col);
    const int nt = row >> 8, rr = row & 255, t = col >> 6, cc = col & 63;
    f16x4 h = {(_Float16)v.x, (_Float16)v.y, (_Float16)v.z, (_Float16)v.w};
    *(f16x4*)(dst + ((size_t)(nt * 12 + t) * 256 + rr) * 64 + (cc ^ ((rr & 7) << 3))) = h;
}

// ---------------------------------------------------------------------------
// 16-wave 256x256 BK=64 GEMM compute: wave tile 64x64 (4x4 waves), acc 64 VGPR.
// As/Bs: [256][64] halves, swizzle col ^ ((row&7)<<3).
// ---------------------------------------------------------------------------
__device__ __forceinline__ void tile_compute(const _Float16* As, const _Float16* Bs,
                                             int wr, int wc, int l15, int l4,
                                             f32x4 acc[4][4])
{
    #pragma unroll
    for (int ks = 0; ks < 2; ++ks) {
        const int cb = ks * 32 + l4 * 8;
        f16x8 bf[4];
        #pragma unroll
        for (int n = 0; n < 4; ++n) {
            const int row = wc * 64 + n * 16 + l15;
            bf[n] = *(const f16x8*)(Bs + (size_t)row * 64 + (cb ^ ((row & 7) << 3)));
        }
        __builtin_amdgcn_s_setprio(1);
        #pragma unroll
        for (int m = 0; m < 4; ++m) {
            const int row = wr * 64 + m * 16 + l15;
            const f16x8 af = *(const f16x8*)(As + (size_t)row * 64 + (cb ^ ((row & 7) << 3)));
            #pragma unroll
            for (int n = 0; n < 4; ++n)
                acc[m][n] = mfma16(af, bf[n], acc[m][n]);
        }
        __builtin_amdgcn_s_setprio(0);
    }
}

// ---------------------------------------------------------------------------
// Projection GEMM: 1024 thr = 16 waves (4x4), 256x256 tile, BK=64.
// A fp32 reg-staged 1 tile ahead (cvt->swizzled ds_write); B gl16 from image
// 1 tile ahead. Counted vmcnt gates; 2 barriers/tile. 4 waves/SIMD.
// MODE 0: Q linear [bh][n][d] scaled; MODE 1: K half of KVimg;
// MODE 3: V half of KVimg chunked [c][d][8key].  (KVBLK=32)
// ---------------------------------------------------------------------------
template<int MODE>
__global__ __launch_bounds__(1024)
void gemm_p16(const float* __restrict__ A, const _Float16* __restrict__ Wimg,
              _Float16* __restrict__ Y, float scale)
{
    __shared__ __attribute__((aligned(16))) _Float16 Abuf[2][16384];
    __shared__ __attribute__((aligned(16))) _Float16 Bbuf[2][16384];

    const int tid  = threadIdx.x;
    const int wid  = tid >> 6;
    const int lane = tid & 63;
    const int l15  = lane & 15;
    const int l4   = lane >> 4;
    const int wr   = wid >> 2;
    const int wc   = wid & 3;
    const int m0   = blockIdx.x * 256;
    const int nt   = blockIdx.y;

    const unsigned char* Wt = (const unsigned char*)(Wimg + (size_t)nt * 12 * 16384);

    f32x4 acc[4][4];
    #pragma unroll
    for (int m = 0; m < 4; ++m)
        #pragma unroll
        for (int n = 0; n < 4; ++n)
            acc[m][n] = (f32x4){0.f, 0.f, 0.f, 0.f};

    float4 rA[4];
    auto loadA = [&](int t) {
        #pragma unroll
        for (int p = 0; p < 4; ++p) {
            const int linear = p * 1024 + tid;
            const int row = linear >> 4, qc = (linear & 15) * 4;
            rA[p] = *(const float4*)(A + (size_t)(m0 + row) * DIMC + t * 64 + qc);
        }
    };
    auto writeA = [&](int buf) {
        #pragma unroll
        for (int p = 0; p < 4; ++p) {
            const int linear = p * 1024 + tid;
            const int row = linear >> 4, qc = (linear & 15) * 4;
            f16x4 h = {(_Float16)rA[p].x, (_Float16)rA[p].y,
                       (_Float16)rA[p].z, (_Float16)rA[p].w};
            *(f16x4*)(&Abuf[buf][row * 64 + (qc ^ ((row & 7) << 3))]) = h;
        }
    };
    auto stageB = [&](int t) {
        const unsigned char* src = Wt + (size_t)t * 32768;
        #pragma unroll
        for (int u = 0; u < 2; ++u)
            gl16(src + u * 16384 + tid * 16, &Bbuf[t & 1][u * 8192 + tid * 8]);
    };

    // prologue: B(0), A(0); drain; write A(0); issue A(1)
    stageB(0);
    loadA(0);
    asm volatile("s_waitcnt vmcnt(0)" ::: "memory");
    writeA(0);
    loadA(1);                     // A(1) in flight across tile 0
    asm volatile("s_waitcnt lgkmcnt(0)" ::: "memory");
    __builtin_amdgcn_s_barrier();

    for (int t = 0; t < 12; ++t) {
        const _Float16* As = &Abuf[t & 1][0];
        const _Float16* Bs = &Bbuf[t & 1][0];

        if (t < 11) {
            // gate A(t+1) regs (only those are outstanding here: full-tile cover)
            asm volatile("s_waitcnt vmcnt(0)" ::: "memory");
            stageB(t + 1);                    // B(t+1): issued now, gated at tile end
            writeA((t + 1) & 1);              // cvt + swizzled ds_write
            if (t < 10) loadA(t + 2);         // A(t+2) in flight
        }

        tile_compute(As, Bs, wr, wc, l15, l4, acc);

        if (t < 10)       asm volatile("s_waitcnt vmcnt(4)" ::: "memory"); // B(t+1) done
        else if (t == 10) asm volatile("s_waitcnt vmcnt(0)" ::: "memory");
        asm volatile("s_waitcnt lgkmcnt(0)" ::: "memory");
        __builtin_amdgcn_s_barrier();
    }

    // epilogue
    #pragma unroll
    for (int m = 0; m < 4; ++m) {
        const int rbase = m0 + wr * 64 + m * 16 + l4 * 4;
        #pragma unroll
        for (int n = 0; n < 4; ++n) {
            const int c = nt * 256 + wc * 64 + n * 16 + l15;
            const int h = c / HD;
            const int d = c - h * HD;
            #pragma unroll
            for (int j = 0; j < 4; ++j) {
                const int r  = rbase + j;
                const int b  = r >> 11;
                const int nn = r & (SEQ - 1);
                if (MODE == 0) {
                    Y[((size_t)(b * NH + h) * SEQ + nn) * HD + d] =
                        (_Float16)(acc[m][n][j] * scale);
                } else {
                    const int kt  = nn >> 5;
                    const int key = nn & 31;
                    const size_t tb = ((size_t)(b * NH + h) * 64 + kt) * 12288;
                    size_t idx;
                    if (MODE == 1)
                        idx = tb + (size_t)key * HD + (d ^ ((key & 7) << 3));
                    else
                        idx = tb + 6144 + (((size_t)(key >> 3) * 192 + d) << 3) + (key & 7);
                    Y[idx] = (_Float16)acc[m][n][j];
                }
            }
        }
    }
}

// ---------------------------------------------------------------------------
// Final GEMM: 16-wave 256x256, both operands fp16 images via gl16.
// ---------------------------------------------------------------------------
__global__ __launch_bounds__(1024)
void gemm_x16(const _Float16* __restrict__ Ximg, const _Float16* __restrict__ Wimg,
              float* __restrict__ out, const float* __restrict__ bias)
{
    __shared__ __attribute__((aligned(16))) _Float16 Abuf[2][16384];
    __shared__ __attribute__((aligned(16))) _Float16 Bbuf[2][16384];

    const int tid  = threadIdx.x;
    const int wid  = tid >> 6;
    const int lane = tid & 63;
    const int l15  = lane & 15;
    const int l4   = lane >> 4;
    const int wr   = wid >> 2;
    const int wc   = wid & 3;
    const int mt   = blockIdx.x;
    const int nt   = blockIdx.y;

    const unsigned char* Xt = (const unsigned char*)(Ximg + (size_t)mt * 12 * 16384);
    const unsigned char* Wt = (const unsigned char*)(Wimg + (size_t)nt * 12 * 16384);

    f32x4 acc[4][4];
    #pragma unroll
    for (int m = 0; m < 4; ++m)
        #pragma unroll
        for (int n = 0; n < 4; ++n)
            acc[m][n] = (f32x4){0.f, 0.f, 0.f, 0.f};

    auto stageAB = [&](int t) {
        const unsigned char* sa = Xt + (size_t)t * 32768;
        const unsigned char* sb = Wt + (size_t)t * 32768;
        #pragma unroll
        for (int u = 0; u < 2; ++u) {
            gl16(sa + u * 16384 + tid * 16, &Abuf[t & 1][u * 8192 + tid * 8]);
            gl16(sb + u * 16384 + tid * 16, &Bbuf[t & 1][u * 8192 + tid * 8]);
        }
    };

    stageAB(0);
    asm volatile("s_waitcnt vmcnt(0)" ::: "memory");
    __builtin_amdgcn_s_barrier();

    for (int t = 0; t < 12; ++t) {
        const _Float16* As = &Abuf[t & 1][0];
        const _Float16* Bs = &Bbuf[t & 1][0];

        if (t < 11) stageAB(t + 1);           // issued now, gated at tile end

        tile_compute(As, Bs, wr, wc, l15, l4, acc);

        if (t < 11) asm volatile("s_waitcnt vmcnt(0)" ::: "memory");
        __builtin_amdgcn_s_barrier();
    }

    #pragma unroll
    for (int m = 0; m < 4; ++m) {
        const int rbase = mt * 256 + wr * 64 + m * 16 + l4 * 4;
        #pragma unroll
        for (int n = 0; n < 4; ++n) {
            const int c = nt * 256 + wc * 64 + n * 16 + l15;
            const float bv = bias[c];
            #pragma unroll
            for (int j = 0; j < 4; ++j)
                out[(size_t)(rbase + j) * DIMC + c] = acc[m][n][j] + bv;
        }
    }
}

// ---------------------------------------------------------------------------
// Flash attention (unchanged from r9): kt-loop unrolled x2 (compile-time LDS
// bases), 512 thr = 8 waves x 16 q-rows, KVBLK=32, 2 blocks/CU, defer-max
// softmax, per-lane lrow partials, conflict-free chunked V.
// ---------------------------------------------------------------------------
__global__ __launch_bounds__(512, 4)
void attn8(const _Float16* __restrict__ Qh, const _Float16* __restrict__ KVimg,
           _Float16* __restrict__ Ximg)
{
    __shared__ __attribute__((aligned(16))) _Float16 KV0[12288]; // K:0..6144, V:6144..
    __shared__ __attribute__((aligned(16))) _Float16 KV1[12288];
    __shared__ __attribute__((aligned(16))) _Float16 Ps[8][16][40];

    const int tid  = threadIdx.x;
    const int wid  = tid >> 6;
    const int lane = tid & 63;
    const int l15  = lane & 15;
    const int l4   = lane >> 4;

    const int bid   = blockIdx.x;
    const int local = bid >> 3;
    const int bh    = (bid & 7) * 4 + (local >> 4);
    const int qt    = local & 15;

    const unsigned char* KVt = (const unsigned char*)KVimg + (size_t)bh * 64 * 24576;

    auto stage = [&](_Float16* dst, int t) {
        const unsigned char* src = KVt + (size_t)t * 24576;
        #pragma unroll
        for (int s = 0; s < 3; ++s)
            gl16(src + (size_t)(s * 512 + tid) * 16, dst + (size_t)(s * 512 + tid) * 8);
    };

    stage(KV0, 0);

    const int q0 = qt * 128 + wid * 16;
    const size_t qbase = (size_t)bh * SEQ * HD;
    f16x8 qf[6];
    #pragma unroll
    for (int kk = 0; kk < 6; ++kk)
        qf[kk] = *(const f16x8*)(Qh + qbase + (size_t)(q0 + l15) * HD + kk * 32 + l4 * 8);

    f32x4 Oacc[12];
    #pragma unroll
    for (int nd = 0; nd < 12; ++nd)
        Oacc[nd] = (f32x4){0.f, 0.f, 0.f, 0.f};
    float mrow[4], lrow[4];
    #pragma unroll
    for (int j = 0; j < 4; ++j) { mrow[j] = -1e30f; lrow[j] = 0.f; }

    auto iter = [&](const _Float16* Kc, const _Float16* Vc,
                    _Float16* stageDst, int nextT, bool doStage) {
        if (doStage) {
            stage(stageDst, nextT);
            asm volatile("s_waitcnt vmcnt(3)" ::: "memory");
        } else {
            asm volatile("s_waitcnt vmcnt(0)" ::: "memory");
        }
        __builtin_amdgcn_s_barrier();
        __builtin_amdgcn_sched_barrier(0);

        // ---- S = Q K^T ----
        f32x4 sacc[2];
        sacc[0] = (f32x4){0.f, 0.f, 0.f, 0.f};
        sacc[1] = (f32x4){0.f, 0.f, 0.f, 0.f};
        __builtin_amdgcn_s_setprio(1);
        #pragma unroll
        for (int kk = 0; kk < 6; ++kk) {
            const int cb = (kk * 32 + l4 * 8) ^ ((l15 & 7) << 3);
            #pragma unroll
            for (int nn = 0; nn < 2; ++nn) {
                const f16x8 kf = *(const f16x8*)(Kc + (size_t)(nn * 16 + l15) * HD + cb);
                sacc[nn] = mfma16(qf[kk], kf, sacc[nn]);
            }
        }
        __builtin_amdgcn_s_setprio(0);

        // ---- defer-max online softmax ----
        float lm[4];
        bool need = false;
        #pragma unroll
        for (int j = 0; j < 4; ++j) {
            lm[j] = fmaxf(sacc[0][j], sacc[1][j]);
            need |= (lm[j] > mrow[j] + DEFER_THR);
        }
        if (__any(need)) {
            #pragma unroll
            for (int j = 0; j < 4; ++j) {
                float v = lm[j];
                v = fmaxf(v, __shfl_xor(v, 1));
                v = fmaxf(v, __shfl_xor(v, 2));
                v = fmaxf(v, __shfl_xor(v, 4));
                v = fmaxf(v, __shfl_xor(v, 8));
                const float mnew = fmaxf(mrow[j], v);
                const float f    = exp2_hw(mrow[j] - mnew);
                mrow[j] = mnew;
                lrow[j] *= f;
                #pragma unroll
                for (int nd = 0; nd < 12; ++nd)
                    Oacc[nd][j] *= f;
            }
        }
        #pragma unroll
        for (int j = 0; j < 4; ++j) {
            const float p0 = exp2_hw(sacc[0][j] - mrow[j]);
            const float p1 = exp2_hw(sacc[1][j] - mrow[j]);
            sacc[0][j] = p0;
            sacc[1][j] = p1;
            lrow[j] += p0 + p1;
        }

        // ---- P -> per-wave LDS -> A-frag ----
        #pragma unroll
        for (int nn = 0; nn < 2; ++nn)
            #pragma unroll
            for (int j = 0; j < 4; ++j)
                Ps[wid][l4 * 4 + j][nn * 16 + l15] = (_Float16)sacc[nn][j];
        asm volatile("s_waitcnt lgkmcnt(0)" ::: "memory");
        __builtin_amdgcn_sched_barrier(0);

        // ---- O += P V (chunked V: conflict-free) ----
        const f16x8 pf = *(const f16x8*)(&Ps[wid][l15][l4 * 8]);
        __builtin_amdgcn_s_setprio(1);
        #pragma unroll
        for (int nd = 0; nd < 12; ++nd) {
            const f16x8 vfr = *(const f16x8*)(Vc + (((size_t)l4 * 192 + nd * 16 + l15) << 3));
            Oacc[nd] = mfma16(pf, vfr, Oacc[nd]);
        }
        __builtin_amdgcn_s_setprio(0);

        __builtin_amdgcn_s_barrier();
        __builtin_amdgcn_sched_barrier(0);
    };

    for (int kt = 0; kt < SEQ / 32; kt += 2) {
        iter(&KV0[0], &KV0[6144], KV1, kt + 1, true);
        iter(&KV1[0], &KV1[6144], KV0, kt + 2, kt + 2 < SEQ / 32);
    }

    // epilogue: reduce lrow, write 256-row-tile X image
    #pragma unroll
    for (int j = 0; j < 4; ++j) {
        float s = lrow[j];
        s += __shfl_xor(s, 1);
        s += __shfl_xor(s, 2);
        s += __shfl_xor(s, 4);
        s += __shfl_xor(s, 8);
        lrow[j] = s;
    }
    const int b = bh >> 2;
    const int h = bh & 3;
    #pragma unroll
    for (int j = 0; j < 4; ++j) {
        const float inv = 1.f / lrow[j];
        const int qrow = q0 + l4 * 4 + j;
        const int gr   = b * SEQ + qrow;
        const int mt   = gr >> 8;
        const int rr   = gr & 255;
        #pragma unroll
        for (int nd = 0; nd < 12; ++nd) {
            const int gc = h * HD + nd * 16 + l15;
            const int t  = gc >> 6;
            const int cc = gc & 63;
            Ximg[((size_t)(mt * 12 + t) * 256 + rr) * 64 + (cc ^ ((rr & 7) << 3))] =
                (_Float16)(Oacc[nd][j] * inv);
        }
    }
}

// ---------------------------------------------------------------------------
extern "C" void kernel_launch(void* const* d_in, const int* in_sizes, int n_in,
                              void* d_out, int out_size, void* d_ws, size_t ws_size,
                              hipStream_t stream)
{
    const float* q  = (const float*)d_in[0];
    const float* k  = (const float*)d_in[1];
    const float* v  = (const float*)d_in[2];
    const float* Wq = (const float*)d_in[3];
    const float* Wk = (const float*)d_in[4];
    const float* Wv = (const float*)d_in[5];
    const float* Wp = (const float*)d_in[6];
    const float* bp = (const float*)d_in[7];

    const size_t HSZ  = (size_t)NBATCH * NH * SEQ * HD;  // 12,582,912
    const size_t WIMG = 3 * 12 * 16384;                  // 589,824 halves
    _Float16* Qh    = (_Float16*)d_ws;
    _Float16* KVimg = Qh + HSZ;          // 2*HSZ halves
    _Float16* Ximg  = KVimg + 2 * HSZ;
    _Float16* Wpimg = Ximg + HSZ;        // ~101.8 MB total ws
    _Float16* Wqimg = (_Float16*)d_out;  // d_out scratch until final GEMM
    _Float16* Wkimg = Wqimg + WIMG;
    _Float16* Wvimg = Wkimg + WIMG;

    cvt_w<<<dim3(576, 4), dim3(256), 0, stream>>>(Wq, Wk, Wv, Wp,
                                                  Wqimg, Wkimg, Wvimg, Wpimg);
    dim3 g16(64, 3), b16(1024);
    gemm_p16<0><<<g16, b16, 0, stream>>>(q, Wqimg, Qh, SCALE_F * LOG2E);
    gemm_p16<1><<<g16, b16, 0, stream>>>(k, Wkimg, KVimg, 1.0f);
    gemm_p16<3><<<g16, b16, 0, stream>>>(v, Wvimg, KVimg, 1.0f);
    attn8<<<dim3(512), dim3(512), 0, stream>>>(Qh, KVimg, Ximg);
    gemm_x16<<<g16, b16, 0, stream>>>(Ximg, Wpimg, (float*)d_out, bp);
}

// Round 11
// 243.022 us; speedup vs baseline: 1.1611x; 1.1611x over previous
//
#include <hip/hip_runtime.h>
#include <hip/hip_fp16.h>

#define DIMC 768
#define NH 4
#define HD 192
#define SEQ 2048
#define NBATCH 8
#define SCALE_F 0.07216878364870323f  /* 192^-0.5 */
#define LOG2E   1.4426950408889634f
#define DEFER_THR 8.0f                /* log2-domain defer-max threshold */

typedef _Float16 f16x8 __attribute__((ext_vector_type(8)));
typedef _Float16 f16x4 __attribute__((ext_vector_type(4)));
typedef float    f32x4 __attribute__((ext_vector_type(4)));

__device__ __forceinline__ f32x4 mfma16(f16x8 a, f16x8 b, f32x4 c) {
    return __builtin_amdgcn_mfma_f32_16x16x32_f16(a, b, c, 0, 0, 0);
}
__device__ __forceinline__ void gl16(const void* g, void* l) {
    __builtin_amdgcn_global_load_lds(
        (const __attribute__((address_space(1))) unsigned int*)g,
        (__attribute__((address_space(3))) unsigned int*)l, 16, 0, 0);
}
__device__ __forceinline__ float exp2_hw(float x) {
    return __builtin_amdgcn_exp2f(x);
}

// ---------------------------------------------------------------------------
// cvt_w: fp32 W[768][768] -> fp16 pre-swizzled 192-row tile images.
// idx = ((nt*12 + t)*192 + rr)*64 + (cc ^ ((rr&7)<<3));
//   nt = row/192, rr = row%192, t = col>>6, cc = col&63.   (4 n-tiles of 192)
// ---------------------------------------------------------------------------
__global__ __launch_bounds__(256)
void cvt_w(const float* __restrict__ w0, const float* __restrict__ w1,
           const float* __restrict__ w2, const float* __restrict__ w3,
           _Float16* __restrict__ o0, _Float16* __restrict__ o1,
           _Float16* __restrict__ o2, _Float16* __restrict__ o3)
{
    const float* src = (blockIdx.y == 0) ? w0 : (blockIdx.y == 1) ? w1
                     : (blockIdx.y == 2) ? w2 : w3;
    _Float16* dst = (blockIdx.y == 0) ? o0 : (blockIdx.y == 1) ? o1
                  : (blockIdx.y == 2) ? o2 : o3;
    const int e   = blockIdx.x * 256 + threadIdx.x;
    const int row = e / 192;
    const int col = (e - row * 192) * 4;
    const float4 v = *(const float4*)(src + (size_t)row * DIMC + col);
    const int nt = row / 192, rr = row - nt * 192;
    const int t  = col >> 6,  cc = col & 63;
    f16x4 h = {(_Float16)v.x, (_Float16)v.y, (_Float16)v.z, (_Float16)v.w};
    *(f16x4*)(dst + ((size_t)(nt * 12 + t) * 192 + rr) * 64 + (cc ^ ((rr & 7) << 3))) = h;
}

// ---------------------------------------------------------------------------
// 8-phase 256x192 GEMM helpers: 8 waves (2M x 4N), wave tile 128x48 (NF=3).
// As: [256][64], Bs: [192][64], swizzle col ^ ((row&7)<<3).
// ---------------------------------------------------------------------------
__device__ __forceinline__ void phase_reads(const _Float16* As, const _Float16* Bs,
                                            int wr, int wc, int l15, int l4, int q,
                                            f16x8 af[2][2], f16x8 bf[2][3], bool loadB)
{
    #pragma unroll
    for (int ks = 0; ks < 2; ++ks) {
        const int cb = ks * 32 + l4 * 8;
        #pragma unroll
        for (int mm = 0; mm < 2; ++mm) {
            const int row = wr * 128 + (q * 2 + mm) * 16 + l15;
            af[ks][mm] = *(const f16x8*)(As + (size_t)row * 64 + (cb ^ ((row & 7) << 3)));
        }
        if (loadB) {
            #pragma unroll
            for (int n = 0; n < 3; ++n) {
                const int row = wc * 48 + n * 16 + l15;
                bf[ks][n] = *(const f16x8*)(Bs + (size_t)row * 64 + (cb ^ ((row & 7) << 3)));
            }
        }
    }
}
__device__ __forceinline__ void phase_mfma(int q, f16x8 af[2][2], f16x8 bf[2][3],
                                           f32x4 acc[8][3])
{
    __builtin_amdgcn_s_barrier();
    asm volatile("s_waitcnt lgkmcnt(0)" ::: "memory");
    __builtin_amdgcn_s_setprio(1);
    #pragma unroll
    for (int ks = 0; ks < 2; ++ks)
        #pragma unroll
        for (int mm = 0; mm < 2; ++mm)
            #pragma unroll
            for (int n = 0; n < 3; ++n)
                acc[q * 2 + mm][n] = mfma16(af[ks][mm], bf[ks][n], acc[q * 2 + mm][n]);
    __builtin_amdgcn_s_setprio(0);
}

// ---------------------------------------------------------------------------
// Projection GEMM (8-phase, 256x192, grid 64x4 = 256 = 1/CU):
// A fp32 reg-staged (cvt->swizzled ds_write), B gl16 from 192-tile image.
// MODE 0: Q linear [bh][n][d] scaled; MODE 1: K half of KVimg;
// MODE 3: V half of KVimg chunked [c][d][8key].  (KVBLK=32; h = nt)
// ---------------------------------------------------------------------------
template<int MODE>
__global__ __launch_bounds__(512, 2)
void gemm_p8(const float* __restrict__ A, const _Float16* __restrict__ Wimg,
             _Float16* __restrict__ Y, float scale)
{
    __shared__ __attribute__((aligned(16))) _Float16 Abuf[2][16384];
    __shared__ __attribute__((aligned(16))) _Float16 Bbuf[2][12288];

    const int tid  = threadIdx.x;
    const int wid  = tid >> 6;
    const int lane = tid & 63;
    const int l15  = lane & 15;
    const int l4   = lane >> 4;
    const int wr   = wid >> 2;
    const int wc   = wid & 3;
    const int m0   = blockIdx.x * 256;
    const int nt   = blockIdx.y;

    const unsigned char* Wt = (const unsigned char*)(Wimg + (size_t)nt * 12 * 12288);

    f32x4 acc[8][3];
    #pragma unroll
    for (int m = 0; m < 8; ++m)
        #pragma unroll
        for (int n = 0; n < 3; ++n)
            acc[m][n] = (f32x4){0.f, 0.f, 0.f, 0.f};

    float4 rA[8];
    auto loadA = [&](int t) {
        #pragma unroll
        for (int p = 0; p < 8; ++p) {
            const int linear = p * 512 + tid;
            const int row = linear >> 4, qc = (linear & 15) * 4;
            rA[p] = *(const float4*)(A + (size_t)(m0 + row) * DIMC + t * 64 + qc);
        }
    };
    auto writeA = [&](int buf) {
        #pragma unroll
        for (int p = 0; p < 8; ++p) {
            const int linear = p * 512 + tid;
            const int row = linear >> 4, qc = (linear & 15) * 4;
            f16x4 h = {(_Float16)rA[p].x, (_Float16)rA[p].y,
                       (_Float16)rA[p].z, (_Float16)rA[p].w};
            *(f16x4*)(&Abuf[buf][row * 64 + (qc ^ ((row & 7) << 3))]) = h;
        }
    };
    auto stageB = [&](int t) {
        const unsigned char* src = Wt + (size_t)t * 24576;
        #pragma unroll
        for (int u = 0; u < 3; ++u)
            gl16(src + u * 8192 + tid * 16, &Bbuf[t & 1][u * 4096 + tid * 8]);
    };

    // prologue
    loadA(0);
    stageB(0);
    asm volatile("s_waitcnt vmcnt(3)" ::: "memory");   // A(0) landed (3 B fly)
    writeA(0);
    loadA(1);
    asm volatile("s_waitcnt vmcnt(8)" ::: "memory");   // B(0) landed (8 A fly)
    asm volatile("s_waitcnt lgkmcnt(0)" ::: "memory");
    __builtin_amdgcn_s_barrier();

    for (int t = 0; t < 12; ++t) {
        const _Float16* As = &Abuf[t & 1][0];
        const _Float16* Bs = &Bbuf[t & 1][0];
        f16x8 af[2][2], bf[2][3];

        phase_reads(As, Bs, wr, wc, l15, l4, 0, af, bf, true);
        if (t < 11) stageB(t + 1);
        phase_mfma(0, af, bf, acc);
        __builtin_amdgcn_s_barrier();

        phase_reads(As, Bs, wr, wc, l15, l4, 1, af, bf, false);
        phase_mfma(1, af, bf, acc);
        __builtin_amdgcn_s_barrier();

        phase_reads(As, Bs, wr, wc, l15, l4, 2, af, bf, false);
        if (t < 11) {
            asm volatile("s_waitcnt vmcnt(3)" ::: "memory");  // A(t+1) landed
            writeA((t + 1) & 1);
            if (t < 10) loadA(t + 2);
        }
        phase_mfma(2, af, bf, acc);
        __builtin_amdgcn_s_barrier();

        phase_reads(As, Bs, wr, wc, l15, l4, 3, af, bf, false);
        phase_mfma(3, af, bf, acc);
        if (t < 10)       asm volatile("s_waitcnt vmcnt(8)" ::: "memory");
        else if (t == 10) asm volatile("s_waitcnt vmcnt(0)" ::: "memory");
        __builtin_amdgcn_s_barrier();
    }

    // epilogue: h = nt, d = wc*48 + n*16 + l15
    #pragma unroll
    for (int m = 0; m < 8; ++m) {
        const int rbase = m0 + wr * 128 + m * 16 + l4 * 4;
        #pragma unroll
        for (int n = 0; n < 3; ++n) {
            const int d = wc * 48 + n * 16 + l15;
            #pragma unroll
            for (int j = 0; j < 4; ++j) {
                const int r  = rbase + j;
                const int b  = r >> 11;
                const int nn = r & (SEQ - 1);
                if (MODE == 0) {
                    Y[((size_t)(b * NH + nt) * SEQ + nn) * HD + d] =
                        (_Float16)(acc[m][n][j] * scale);
                } else {
                    const int kt  = nn >> 5;
                    const int key = nn & 31;
                    const size_t tb = ((size_t)(b * NH + nt) * 64 + kt) * 12288;
                    size_t idx;
                    if (MODE == 1)
                        idx = tb + (size_t)key * HD + (d ^ ((key & 7) << 3));
                    else
                        idx = tb + 6144 + (((size_t)(key >> 3) * 192 + d) << 3) + (key & 7);
                    Y[idx] = (_Float16)acc[m][n][j];
                }
            }
        }
    }
}

// ---------------------------------------------------------------------------
// Final GEMM (8-phase, 256x192, grid 64x4): out = Ximg @ Wp.T + bias.
// Both operands fp16 images via gl16 (A: 256x64 tiles, B: 192x64 tiles).
// ---------------------------------------------------------------------------
__global__ __launch_bounds__(512, 2)
void gemm_x8(const _Float16* __restrict__ Ximg, const _Float16* __restrict__ Wimg,
             float* __restrict__ out, const float* __restrict__ bias)
{
    __shared__ __attribute__((aligned(16))) _Float16 Abuf[2][16384];
    __shared__ __attribute__((aligned(16))) _Float16 Bbuf[2][12288];

    const int tid  = threadIdx.x;
    const int wid  = tid >> 6;
    const int lane = tid & 63;
    const int l15  = lane & 15;
    const int l4   = lane >> 4;
    const int wr   = wid >> 2;
    const int wc   = wid & 3;
    const int mt   = blockIdx.x;
    const int nt   = blockIdx.y;

    const unsigned char* Xt = (const unsigned char*)(Ximg + (size_t)mt * 12 * 16384);
    const unsigned char* Wt = (const unsigned char*)(Wimg + (size_t)nt * 12 * 12288);

    f32x4 acc[8][3];
    #pragma unroll
    for (int m = 0; m < 8; ++m)
        #pragma unroll
        for (int n = 0; n < 3; ++n)
            acc[m][n] = (f32x4){0.f, 0.f, 0.f, 0.f};

    auto stageAB = [&](int t) {
        const unsigned char* sa = Xt + (size_t)t * 32768;
        const unsigned char* sb = Wt + (size_t)t * 24576;
        #pragma unroll
        for (int u = 0; u < 4; ++u)
            gl16(sa + u * 8192 + tid * 16, &Abuf[t & 1][u * 4096 + tid * 8]);
        #pragma unroll
        for (int u = 0; u < 3; ++u)
            gl16(sb + u * 8192 + tid * 16, &Bbuf[t & 1][u * 4096 + tid * 8]);
    };

    stageAB(0);
    asm volatile("s_waitcnt vmcnt(0)" ::: "memory");
    __builtin_amdgcn_s_barrier();

    for (int t = 0; t < 12; ++t) {
        const _Float16* As = &Abuf[t & 1][0];
        const _Float16* Bs = &Bbuf[t & 1][0];
        f16x8 af[2][2], bf[2][3];

        phase_reads(As, Bs, wr, wc, l15, l4, 0, af, bf, true);
        if (t < 11) stageAB(t + 1);
        phase_mfma(0, af, bf, acc);
        __builtin_amdgcn_s_barrier();

        phase_reads(As, Bs, wr, wc, l15, l4, 1, af, bf, false);
        phase_mfma(1, af, bf, acc);
        __builtin_amdgcn_s_barrier();

        phase_reads(As, Bs, wr, wc, l15, l4, 2, af, bf, false);
        phase_mfma(2, af, bf, acc);
        __builtin_amdgcn_s_barrier();

        phase_reads(As, Bs, wr, wc, l15, l4, 3, af, bf, false);
        phase_mfma(3, af, bf, acc);
        if (t < 11) asm volatile("s_waitcnt vmcnt(0)" ::: "memory");
        __builtin_amdgcn_s_barrier();
    }

    #pragma unroll
    for (int m = 0; m < 8; ++m) {
        const int rbase = mt * 256 + wr * 128 + m * 16 + l4 * 4;
        #pragma unroll
        for (int n = 0; n < 3; ++n) {
            const int c = nt * 192 + wc * 48 + n * 16 + l15;
            const float bv = bias[c];
            #pragma unroll
            for (int j = 0; j < 4; ++j)
                out[(size_t)(rbase + j) * DIMC + c] = acc[m][n][j] + bv;
        }
    }
}

// ---------------------------------------------------------------------------
// Flash attention (exact r8 attn7): 512 thr = 8 waves x 16 q-rows, KVBLK=32,
// 2 blocks/CU, gl16 dbuf KV, vmcnt(3) counted, defer-max softmax, per-lane
// lrow partials, conflict-free chunked V.
// ---------------------------------------------------------------------------
__global__ __launch_bounds__(512, 4)
void attn7(const _Float16* __restrict__ Qh, const _Float16* __restrict__ KVimg,
           _Float16* __restrict__ Ximg)
{
    __shared__ __attribute__((aligned(16))) _Float16 KV[2][12288]; // K:0..6144, V:6144..
    __shared__ __attribute__((aligned(16))) _Float16 Ps[8][16][40];

    const int tid  = threadIdx.x;
    const int wid  = tid >> 6;
    const int lane = tid & 63;
    const int l15  = lane & 15;
    const int l4   = lane >> 4;

    const int bid   = blockIdx.x;
    const int local = bid >> 3;
    const int bh    = (bid & 7) * 4 + (local >> 4);
    const int qt    = local & 15;

    const unsigned char* KVt = (const unsigned char*)KVimg + (size_t)bh * 64 * 24576;

    #pragma unroll
    for (int s = 0; s < 3; ++s)
        gl16(KVt + (size_t)(s * 512 + tid) * 16, &KV[0][(size_t)(s * 512 + tid) * 8]);

    const int q0 = qt * 128 + wid * 16;
    const size_t qbase = (size_t)bh * SEQ * HD;
    f16x8 qf[6];
    #pragma unroll
    for (int kk = 0; kk < 6; ++kk)
        qf[kk] = *(const f16x8*)(Qh + qbase + (size_t)(q0 + l15) * HD + kk * 32 + l4 * 8);

    f32x4 Oacc[12];
    #pragma unroll
    for (int nd = 0; nd < 12; ++nd)
        Oacc[nd] = (f32x4){0.f, 0.f, 0.f, 0.f};
    float mrow[4], lrow[4];
    #pragma unroll
    for (int j = 0; j < 4; ++j) { mrow[j] = -1e30f; lrow[j] = 0.f; }

    for (int kt = 0; kt < SEQ / 32; ++kt) {
        const int cur = kt & 1;
        if (kt < SEQ / 32 - 1) {
            const unsigned char* KVn = KVt + (size_t)(kt + 1) * 24576;
            #pragma unroll
            for (int s = 0; s < 3; ++s)
                gl16(KVn + (size_t)(s * 512 + tid) * 16,
                     &KV[cur ^ 1][(size_t)(s * 512 + tid) * 8]);
            asm volatile("s_waitcnt vmcnt(3)" ::: "memory");
        } else {
            asm volatile("s_waitcnt vmcnt(0)" ::: "memory");
        }
        __builtin_amdgcn_s_barrier();
        __builtin_amdgcn_sched_barrier(0);

        const _Float16* Kc = &KV[cur][0];
        const _Float16* Vc = &KV[cur][6144];

        // ---- S = Q K^T ----
        f32x4 sacc[2];
        sacc[0] = (f32x4){0.f, 0.f, 0.f, 0.f};
        sacc[1] = (f32x4){0.f, 0.f, 0.f, 0.f};
        __builtin_amdgcn_s_setprio(1);
        #pragma unroll
        for (int kk = 0; kk < 6; ++kk) {
            const int cb = (kk * 32 + l4 * 8) ^ ((l15 & 7) << 3);
            #pragma unroll
            for (int nn = 0; nn < 2; ++nn) {
                const f16x8 kf = *(const f16x8*)(Kc + (size_t)(nn * 16 + l15) * HD + cb);
                sacc[nn] = mfma16(qf[kk], kf, sacc[nn]);
            }
        }
        __builtin_amdgcn_s_setprio(0);

        // ---- defer-max online softmax ----
        float lm[4];
        bool need = false;
        #pragma unroll
        for (int j = 0; j < 4; ++j) {
            lm[j] = fmaxf(sacc[0][j], sacc[1][j]);
            need |= (lm[j] > mrow[j] + DEFER_THR);
        }
        if (__any(need)) {
            #pragma unroll
            for (int j = 0; j < 4; ++j) {
                float v = lm[j];
                v = fmaxf(v, __shfl_xor(v, 1));
                v = fmaxf(v, __shfl_xor(v, 2));
                v = fmaxf(v, __shfl_xor(v, 4));
                v = fmaxf(v, __shfl_xor(v, 8));
                const float mnew = fmaxf(mrow[j], v);
                const float f    = exp2_hw(mrow[j] - mnew);
                mrow[j] = mnew;
                lrow[j] *= f;
                #pragma unroll
                for (int nd = 0; nd < 12; ++nd)
                    Oacc[nd][j] *= f;
            }
        }
        #pragma unroll
        for (int j = 0; j < 4; ++j) {
            const float p0 = exp2_hw(sacc[0][j] - mrow[j]);
            const float p1 = exp2_hw(sacc[1][j] - mrow[j]);
            sacc[0][j] = p0;
            sacc[1][j] = p1;
            lrow[j] += p0 + p1;
        }

        // ---- P -> per-wave LDS -> A-frag ----
        #pragma unroll
        for (int nn = 0; nn < 2; ++nn)
            #pragma unroll
            for (int j = 0; j < 4; ++j)
                Ps[wid][l4 * 4 + j][nn * 16 + l15] = (_Float16)sacc[nn][j];
        asm volatile("s_waitcnt lgkmcnt(0)" ::: "memory");
        __builtin_amdgcn_sched_barrier(0);

        // ---- O += P V (chunked V: conflict-free) ----
        const f16x8 pf = *(const f16x8*)(&Ps[wid][l15][l4 * 8]);
        __builtin_amdgcn_s_setprio(1);
        #pragma unroll
        for (int nd = 0; nd < 12; ++nd) {
            const f16x8 vfr = *(const f16x8*)(Vc + (((size_t)l4 * 192 + nd * 16 + l15) << 3));
            Oacc[nd] = mfma16(pf, vfr, Oacc[nd]);
        }
        __builtin_amdgcn_s_setprio(0);

        __builtin_amdgcn_s_barrier();
        __builtin_amdgcn_sched_barrier(0);
    }

    // epilogue: reduce lrow, write 256-row-tile X image
    #pragma unroll
    for (int j = 0; j < 4; ++j) {
        float s = lrow[j];
        s += __shfl_xor(s, 1);
        s += __shfl_xor(s, 2);
        s += __shfl_xor(s, 4);
        s += __shfl_xor(s, 8);
        lrow[j] = s;
    }
    const int b = bh >> 2;
    const int h = bh & 3;
    #pragma unroll
    for (int j = 0; j < 4; ++j) {
        const float inv = 1.f / lrow[j];
        const int qrow = q0 + l4 * 4 + j;
        const int gr   = b * SEQ + qrow;
        const int mt   = gr >> 8;
        const int rr   = gr & 255;
        #pragma unroll
        for (int nd = 0; nd < 12; ++nd) {
            const int gc = h * HD + nd * 16 + l15;
            const int t  = gc >> 6;
            const int cc = gc & 63;
            Ximg[((size_t)(mt * 12 + t) * 256 + rr) * 64 + (cc ^ ((rr & 7) << 3))] =
                (_Float16)(Oacc[nd][j] * inv);
        }
    }
}

// ---------------------------------------------------------------------------
extern "C" void kernel_launch(void* const* d_in, const int* in_sizes, int n_in,
                              void* d_out, int out_size, void* d_ws, size_t ws_size,
                              hipStream_t stream)
{
    const float* q  = (const float*)d_in[0];
    const float* k  = (const float*)d_in[1];
    const float* v  = (const float*)d_in[2];
    const float* Wq = (const float*)d_in[3];
    const float* Wk = (const float*)d_in[4];
    const float* Wv = (const float*)d_in[5];
    const float* Wp = (const float*)d_in[6];
    const float* bp = (const float*)d_in[7];

    const size_t HSZ  = (size_t)NBATCH * NH * SEQ * HD;  // 12,582,912
    const size_t WIMG = 4 * 12 * 12288;                  // 589,824 halves
    _Float16* Qh    = (_Float16*)d_ws;
    _Float16* KVimg = Qh + HSZ;          // 2*HSZ halves
    _Float16* Ximg  = KVimg + 2 * HSZ;
    _Float16* Wpimg = Ximg + HSZ;        // ~101.8 MB total ws
    _Float16* Wqimg = (_Float16*)d_out;  // d_out scratch until final GEMM
    _Float16* Wkimg = Wqimg + WIMG;
    _Float16* Wvimg = Wkimg + WIMG;

    cvt_w<<<dim3(576, 4), dim3(256), 0, stream>>>(Wq, Wk, Wv, Wp,
                                                  Wqimg, Wkimg, Wvimg, Wpimg);
    dim3 g8(64, 4), b8(512);
    gemm_p8<0><<<g8, b8, 0, stream>>>(q, Wqimg, Qh, SCALE_F * LOG2E);
    gemm_p8<1><<<g8, b8, 0, stream>>>(k, Wkimg, KVimg, 1.0f);
    gemm_p8<3><<<g8, b8, 0, stream>>>(v, Wvimg, KVimg, 1.0f);
    attn7<<<dim3(512), dim3(512), 0, stream>>>(Qh, KVimg, Ximg);
    gemm_x8<<<g8, b8, 0, stream>>>(Ximg, Wpimg, (float*)d_out, bp);
}